// Round 1
// baseline (1729.847 us; speedup 1.0000x reference)
//
#include <hip/hip_runtime.h>

#define N_ROWS 100000
#define M_COLS 50000
#define NNODES 150000
#define D 32
#define NEDGE 5000000

// h[i][j] = sum_k act(x[i][k]) * W[j][k] + b[j]; writes H and AGG (AGG init = self-loop)
// MODE 0: x = concat(row_embed, col_embed), no activation.
// MODE 1: x = xa buffer, ReLU applied on read.
template <int MODE>
__global__ void linear_kernel(const float* __restrict__ xa, const float* __restrict__ xb,
                              const float* __restrict__ W, const float* __restrict__ b,
                              float* __restrict__ H, float* __restrict__ AGG) {
    __shared__ float Wt[D * D];  // Wt[k*D+j] = W[j*D+k]
    __shared__ float bs[D];
    const int tid = threadIdx.x;
    for (int t = tid; t < D * D; t += blockDim.x) {
        int j = t / D, k = t % D;
        Wt[k * D + j] = W[j * D + k];
    }
    if (tid < D) bs[tid] = b[tid];
    __syncthreads();

    const int row = blockIdx.x * (blockDim.x / D) + tid / D;  // 8 rows per 256-thread block
    const int j = tid % D;
    if (row >= NNODES) return;

    float xv;
    if (MODE == 0) {
        xv = (row < N_ROWS) ? xa[row * D + j] : xb[(row - N_ROWS) * D + j];
    } else {
        xv = fmaxf(xa[row * D + j], 0.0f);
    }

    float acc = bs[j];
#pragma unroll
    for (int k = 0; k < D; ++k) {
        float a = __shfl(xv, k, D);  // broadcast x[row][k] within the 32-lane row group
        acc = fmaf(a, Wt[k * D + j], acc);
    }
    H[row * D + j] = acc;
    AGG[row * D + j] = acc;  // self-loop contribution
}

// One (edge, feature) pair per work item: 32 consecutive lanes share an edge.
__global__ void scatter_kernel(const int* __restrict__ src, const int* __restrict__ dst,
                               const float* __restrict__ H, float* __restrict__ AGG) {
    long long g = (long long)blockIdx.x * blockDim.x + threadIdx.x;
    const long long total = (long long)NEDGE * D;
    const long long stride = (long long)gridDim.x * blockDim.x;
    for (; g < total; g += stride) {
        const int e = (int)(g >> 5);
        const int j = (int)(g & 31);
        const int s = src[e];
        const int d = dst[e];
        atomicAdd(&AGG[d * D + j], H[s * D + j]);
    }
}

__global__ void relu_out_kernel(const float* __restrict__ A, float* __restrict__ out) {
    int i = blockIdx.x * blockDim.x + threadIdx.x;
    const int total = NNODES * D;
    const int stride = gridDim.x * blockDim.x;
    for (; i < total; i += stride) {
        out[i] = fmaxf(A[i], 0.0f);
    }
}

extern "C" void kernel_launch(void* const* d_in, const int* in_sizes, int n_in,
                              void* d_out, int out_size, void* d_ws, size_t ws_size,
                              hipStream_t stream) {
    const float* row_embed = (const float*)d_in[0];
    const float* col_embed = (const float*)d_in[1];
    const float* W0 = (const float*)d_in[2];
    const float* b0 = (const float*)d_in[3];
    const float* W1 = (const float*)d_in[4];
    const float* b1 = (const float*)d_in[5];
    const float* W2 = (const float*)d_in[6];
    const float* b2 = (const float*)d_in[7];
    const int* ei = (const int*)d_in[8];
    const int* src = ei;          // edge_index[0]
    const int* dst = ei + NEDGE;  // edge_index[1]
    float* out = (float*)d_out;

    float* H = (float*)d_ws;
    float* A0 = H + (size_t)NNODES * D;
    float* A1 = A0 + (size_t)NNODES * D;

    const dim3 blk(256);
    const int lin_grid = NNODES / 8;  // 150000 / 8 = 18750, exact
    const int sc_grid = 2048;

    // layer 0
    linear_kernel<0><<<lin_grid, blk, 0, stream>>>(row_embed, col_embed, W0, b0, H, A0);
    scatter_kernel<<<sc_grid, blk, 0, stream>>>(src, dst, H, A0);
    // layer 1
    linear_kernel<1><<<lin_grid, blk, 0, stream>>>(A0, nullptr, W1, b1, H, A1);
    scatter_kernel<<<sc_grid, blk, 0, stream>>>(src, dst, H, A1);
    // layer 2
    linear_kernel<1><<<lin_grid, blk, 0, stream>>>(A1, nullptr, W2, b2, H, A0);
    scatter_kernel<<<sc_grid, blk, 0, stream>>>(src, dst, H, A0);
    // output ReLU
    relu_out_kernel<<<2048, blk, 0, stream>>>(A0, out);
}

// Round 2
// 1265.884 us; speedup vs baseline: 1.3665x; 1.3665x over previous
//
#include <hip/hip_runtime.h>

#define N_ROWS 100000
#define NNODES 150000
#define D 32
#define NEDGE 5000000
#define CHUNK 2048
#define NB ((NNODES + CHUNK - 1) / CHUNK)  // 74

// ---------------- CSR build (counting sort by dst) ----------------

__global__ void zero_kernel(int* __restrict__ cnt) {
    int i = blockIdx.x * blockDim.x + threadIdx.x;
    if (i < NNODES) cnt[i] = 0;
}

__global__ void hist_kernel(const int* __restrict__ dst, int* __restrict__ cnt) {
    int i = blockIdx.x * blockDim.x + threadIdx.x;
    const int stride = gridDim.x * blockDim.x;
    for (; i < NEDGE; i += stride) atomicAdd(&cnt[dst[i]], 1);
}

// per-chunk total
__global__ void scan1_kernel(const int* __restrict__ cnt, int* __restrict__ blockSums) {
    __shared__ int s[256];
    const int t = threadIdx.x;
    const int base = blockIdx.x * CHUNK + t * 8;
    int sum = 0;
#pragma unroll
    for (int k = 0; k < 8; ++k) {
        int idx = base + k;
        sum += (idx < NNODES) ? cnt[idx] : 0;
    }
    s[t] = sum;
    __syncthreads();
    for (int off = 128; off > 0; off >>= 1) {
        if (t < off) s[t] += s[t + off];
        __syncthreads();
    }
    if (t == 0) blockSums[blockIdx.x] = s[0];
}

// exclusive scan of the NB chunk totals (single block)
__global__ void scan2_kernel(int* __restrict__ blockSums) {
    __shared__ int s[128];
    const int t = threadIdx.x;  // blockDim = 128, NB <= 128
    s[t] = (t < NB) ? blockSums[t] : 0;
    __syncthreads();
    for (int off = 1; off < 128; off <<= 1) {
        int v = (t >= off) ? s[t - off] : 0;
        __syncthreads();
        s[t] += v;
        __syncthreads();
    }
    if (t < NB) blockSums[t] = (t == 0) ? 0 : s[t - 1];
}

// full exclusive scan -> rowptr, plus a cursor copy for the fill pass
__global__ void scan3_kernel(const int* __restrict__ cnt, const int* __restrict__ blockSums,
                             int* __restrict__ rowptr, int* __restrict__ cursor) {
    __shared__ int s[256];
    const int t = threadIdx.x;
    const int base = blockIdx.x * CHUNK + t * 8;
    int c[8];
    int sum = 0;
#pragma unroll
    for (int k = 0; k < 8; ++k) {
        int idx = base + k;
        c[k] = (idx < NNODES) ? cnt[idx] : 0;
        sum += c[k];
    }
    s[t] = sum;
    __syncthreads();
    for (int off = 1; off < 256; off <<= 1) {
        int v = (t >= off) ? s[t - off] : 0;
        __syncthreads();
        s[t] += v;
        __syncthreads();
    }
    int run = blockSums[blockIdx.x] + ((t == 0) ? 0 : s[t - 1]);
#pragma unroll
    for (int k = 0; k < 8; ++k) {
        int idx = base + k;
        if (idx < NNODES) {
            rowptr[idx] = run;
            cursor[idx] = run;
        }
        run += c[k];
    }
    if (blockIdx.x == 0 && t == 0) rowptr[NNODES] = NEDGE;
}

__global__ void fill_kernel(const int* __restrict__ src, const int* __restrict__ dst,
                            int* __restrict__ cursor, int* __restrict__ srcSorted) {
    int i = blockIdx.x * blockDim.x + threadIdx.x;
    const int stride = gridDim.x * blockDim.x;
    for (; i < NEDGE; i += stride) {
        int pos = atomicAdd(&cursor[dst[i]], 1);
        srcSorted[pos] = src[i];
    }
}

// ---------------- per-layer compute ----------------

// h[i][j] = sum_k act(x[i][k]) * W[j][k] + b[j]
// MODE 0: x = concat(row_embed, col_embed), no activation.
// MODE 1: x = xa buffer, ReLU applied on read.
template <int MODE>
__global__ void linear_kernel(const float* __restrict__ xa, const float* __restrict__ xb,
                              const float* __restrict__ W, const float* __restrict__ b,
                              float* __restrict__ H) {
    __shared__ float Wt[D * D];  // Wt[k*D+j] = W[j*D+k]
    __shared__ float bs[D];
    const int tid = threadIdx.x;
    for (int t = tid; t < D * D; t += blockDim.x) {
        int j = t / D, k = t % D;
        Wt[k * D + j] = W[j * D + k];
    }
    if (tid < D) bs[tid] = b[tid];
    __syncthreads();

    const int row = blockIdx.x * (blockDim.x / D) + tid / D;
    const int j = tid % D;
    if (row >= NNODES) return;

    float xv;
    if (MODE == 0) {
        xv = (row < N_ROWS) ? xa[row * D + j] : xb[(row - N_ROWS) * D + j];
    } else {
        xv = fmaxf(xa[row * D + j], 0.0f);
    }

    float acc = bs[j];
#pragma unroll
    for (int k = 0; k < D; ++k) {
        float a = __shfl(xv, k, D);
        acc = fmaf(a, Wt[k * D + j], acc);
    }
    H[row * D + j] = acc;
}

// One 32-lane group per dst row: acc = H[d] (self-loop) + sum over CSR bucket.
template <bool RELU>
__global__ void agg_kernel(const int* __restrict__ rowptr, const int* __restrict__ srcSorted,
                           const float* __restrict__ H, float* __restrict__ AGG) {
    const int tid = threadIdx.x;
    const int d = blockIdx.x * (blockDim.x >> 5) + (tid >> 5);
    const int j = tid & 31;
    if (d >= NNODES) return;

    int e = rowptr[d];
    const int eEnd = rowptr[d + 1];
    float acc = H[d * D + j];  // self-loop
    for (; e + 1 < eEnd; e += 2) {
        const int s0 = srcSorted[e];
        const int s1 = srcSorted[e + 1];
        const float v0 = H[s0 * D + j];
        const float v1 = H[s1 * D + j];
        acc += v0;
        acc += v1;
    }
    if (e < eEnd) acc += H[srcSorted[e] * D + j];
    AGG[d * D + j] = RELU ? fmaxf(acc, 0.0f) : acc;
}

// ---------------- launch ----------------

extern "C" void kernel_launch(void* const* d_in, const int* in_sizes, int n_in,
                              void* d_out, int out_size, void* d_ws, size_t ws_size,
                              hipStream_t stream) {
    const float* row_embed = (const float*)d_in[0];
    const float* col_embed = (const float*)d_in[1];
    const float* W0 = (const float*)d_in[2];
    const float* b0 = (const float*)d_in[3];
    const float* W1 = (const float*)d_in[4];
    const float* b1 = (const float*)d_in[5];
    const float* W2 = (const float*)d_in[6];
    const float* b2 = (const float*)d_in[7];
    const int* ei = (const int*)d_in[8];
    const int* src = ei;
    const int* dst = ei + NEDGE;
    float* out = (float*)d_out;

    // workspace carve-up (all 4-byte elements)
    float* H = (float*)d_ws;
    float* B0 = H + (size_t)NNODES * D;
    float* B1 = B0 + (size_t)NNODES * D;
    int* cnt = (int*)(B1 + (size_t)NNODES * D);
    int* rowptr = cnt + NNODES;
    int* cursor = rowptr + (NNODES + 1);
    int* blockSums = cursor + NNODES;
    int* srcSorted = blockSums + 128;

    const dim3 blk(256);
    const int lin_grid = (NNODES * D + 255) / 256;  // rows*32 threads / 256
    const int row_grid = (NNODES + 7) / 8;          // 8 rows per block

    // CSR build (per call; ws is not re-initialized by the harness)
    zero_kernel<<<(NNODES + 255) / 256, blk, 0, stream>>>(cnt);
    hist_kernel<<<2048, blk, 0, stream>>>(dst, cnt);
    scan1_kernel<<<NB, blk, 0, stream>>>(cnt, blockSums);
    scan2_kernel<<<1, 128, 0, stream>>>(blockSums);
    scan3_kernel<<<NB, blk, 0, stream>>>(cnt, blockSums, rowptr, cursor);
    fill_kernel<<<2048, blk, 0, stream>>>(src, dst, cursor, srcSorted);

    // layer 0
    linear_kernel<0><<<row_grid, blk, 0, stream>>>(row_embed, col_embed, W0, b0, H);
    agg_kernel<false><<<row_grid, blk, 0, stream>>>(rowptr, srcSorted, H, B0);
    // layer 1
    linear_kernel<1><<<row_grid, blk, 0, stream>>>(B0, nullptr, W1, b1, H);
    agg_kernel<false><<<row_grid, blk, 0, stream>>>(rowptr, srcSorted, H, B1);
    // layer 2 (fused output ReLU)
    linear_kernel<1><<<row_grid, blk, 0, stream>>>(B1, nullptr, W2, b2, H);
    agg_kernel<true><<<row_grid, blk, 0, stream>>>(rowptr, srcSorted, H, out);

    (void)lin_grid;
    (void)in_sizes; (void)n_in; (void)out_size; (void)ws_size;
}